// Round 1
// baseline (346.445 us; speedup 1.0000x reference)
//
#include <hip/hip_runtime.h>

using u32 = unsigned int;
using u16 = unsigned short;

typedef __attribute__((ext_vector_type(8)))  __bf16 bf16x8;
typedef __attribute__((ext_vector_type(16))) float  f32x16;
typedef __attribute__((ext_vector_type(4)))  float  f32x4;
typedef __attribute__((ext_vector_type(4)))  int    i32x4;

__device__ __forceinline__ u32 f2bf(float f){
  u32 u = __float_as_uint(f);
  return (u + 0x7FFFu + ((u >> 16) & 1u)) >> 16;
}
__device__ __forceinline__ u32 pack2bf(float lo, float hi){
  return f2bf(lo) | (f2bf(hi) << 16);
}
__device__ __forceinline__ float bfu2f(u32 us){ return __uint_as_float(us << 16); }
__device__ __forceinline__ float lrelu(float x){ return x > 0.f ? x : 0.01f * x; }

// ---------- K0: weight [512][256] f32 -> wT [256][512] bf16 ----------
__global__ void k0_wt(const float* __restrict__ w, u16* __restrict__ wT){
  int u = blockIdx.x * 256 + threadIdx.x;
  int k = u >> 8, n = u & 255;
  wT[(size_t)n * 512 + k] = (u16)f2bf(w[(size_t)k * 256 + n]);
}

// ---------- K1: out = x @ W, written transposed: outT [256][8192] bf16 ----------
__global__ __launch_bounds__(512, 2) void k1_gemm(const float* __restrict__ x,
    const u16* __restrict__ wT, u16* __restrict__ outT){
  __shared__ float tb[8][32][36];
  const int i0 = blockIdx.x * 32;
  const int lane = threadIdx.x & 63, wv = threadIdx.x >> 6;
  const int r = lane & 31, h = lane >> 5;
  const float* xp = x + (size_t)(i0 + r) * 512 + h * 8;
  const u16*   bp = wT + (size_t)(wv * 32 + r) * 512 + h * 8;
  f32x16 acc = {};
  for (int s = 0; s < 32; ++s){
    f32x4 a0 = *(const f32x4*)xp;
    f32x4 a1 = *(const f32x4*)(xp + 4);
    i32x4 pk = { (int)pack2bf(a0[0], a0[1]), (int)pack2bf(a0[2], a0[3]),
                 (int)pack2bf(a1[0], a1[1]), (int)pack2bf(a1[2], a1[3]) };
    bf16x8 af = __builtin_bit_cast(bf16x8, pk);
    bf16x8 bf = *(const bf16x8*)bp;
    acc = __builtin_amdgcn_mfma_f32_32x32x16_bf16(af, bf, acc, 0, 0, 0);
    xp += 16; bp += 16;
  }
  // C layout: col(=feature)=lane&31, row(=x-row)=(reg&3)+8*(reg>>2)+4*(lane>>5)
  #pragma unroll
  for (int re = 0; re < 16; ++re){
    int rr = (re & 3) + 8 * (re >> 2) + 4 * h;
    tb[wv][r][rr] = acc[re];
  }
  __syncthreads();
  const int n2 = lane >> 1, ic = (lane & 1) * 16;
  const float* tp = &tb[wv][n2][ic];
  i32x4 w0 = { (int)pack2bf(tp[0],tp[1]),   (int)pack2bf(tp[2],tp[3]),
               (int)pack2bf(tp[4],tp[5]),   (int)pack2bf(tp[6],tp[7]) };
  i32x4 w1 = { (int)pack2bf(tp[8],tp[9]),   (int)pack2bf(tp[10],tp[11]),
               (int)pack2bf(tp[12],tp[13]), (int)pack2bf(tp[14],tp[15]) };
  u16* op = outT + (size_t)(wv * 32 + n2) * 8192 + i0 + ic;
  *(i32x4*)op = w0;
  *((i32x4*)op + 1) = w1;
}

// ---------- K2a: s1[i] = sum_n outT[n][i]*a1[n], s2 likewise ----------
__global__ void k2a_s(const u16* __restrict__ outT, const float* __restrict__ av,
                      float* __restrict__ s1, float* __restrict__ s2){
  int i = blockIdx.x * 64 + threadIdx.x;
  float acc1 = 0.f, acc2 = 0.f;
  #pragma unroll 16
  for (int n = 0; n < 256; ++n){
    float o = bfu2f(outT[(size_t)n * 8192 + i]);
    acc1 = fmaf(o, av[n], acc1);
    acc2 = fmaf(o, av[256 + n], acc2);
  }
  s1[i] = acc1; s2[i] = acc2;
}

// ---------- K2b: v0,v1 (top row scores), p = exp(w - max w) (bottom col weights) ----------
__global__ __launch_bounds__(1024) void k2b_p(const float* __restrict__ s1, const float* __restrict__ s2,
    float* __restrict__ v0, float* __restrict__ v1,
    u16* __restrict__ pbf, u16* __restrict__ pones){
  __shared__ float red[1024];
  const int t = threadIdx.x;
  float wv_[4]; float mx = -1e30f;
  #pragma unroll
  for (int q = 0; q < 4; ++q){
    int k = t + q * 1024;
    float sa = s1[2*k], sb0 = s2[2*k], sa1 = s1[2*k+1], sb1 = s2[2*k+1];
    v0[k] = lrelu(sa + sb0);
    v1[k] = lrelu(sa1 + sb1);
    float ww = lrelu(sa + sb1);
    wv_[q] = ww; mx = fmaxf(mx, ww);
  }
  red[t] = mx; __syncthreads();
  for (int off = 512; off > 0; off >>= 1){
    if (t < off) red[t] = fmaxf(red[t], red[t + off]);
    __syncthreads();
  }
  float M = red[0];
  #pragma unroll
  for (int q = 0; q < 4; ++q){
    int k = t + q * 1024;
    pbf[k]   = (u16)f2bf(__expf(wv_[q] - M));
    pones[k] = (u16)0x3F80;
  }
}

// ---------- K2c: out2T[n][j] = p[j&4095] * outT[n][j] ----------
__global__ void k2c_scale(const u16* __restrict__ outT, const u16* __restrict__ pbf,
                          u16* __restrict__ out2T){
  const int u = blockIdx.x * 256 + threadIdx.x;
  const int n = u >> 10;
  const int j8 = (u & 1023) * 8;
  i32x4 ov = *(const i32x4*)(outT + (size_t)n * 8192 + j8);
  i32x4 pv = *(const i32x4*)(pbf + (j8 & 4095));
  i32x4 rv;
  #pragma unroll
  for (int q = 0; q < 4; ++q){
    u32 o = (u32)ov[q], p = (u32)pv[q];
    rv[q] = (int)pack2bf(bfu2f(o & 0xFFFFu) * bfu2f(p & 0xFFFFu),
                         bfu2f(o >> 16)     * bfu2f(p >> 16));
  }
  *(i32x4*)(out2T + (size_t)n * 8192 + j8) = rv;
}

// ---------- K3: main binary-GEMM + softmax-combine + sigmoid ----------
__global__ __launch_bounds__(512, 2) void k3_main(const int* __restrict__ adj,
    const u16* __restrict__ outT, const u16* __restrict__ out2T,
    const u16* __restrict__ pbf, const u16* __restrict__ pones,
    const float* __restrict__ v0, const float* __restrict__ v1,
    float* __restrict__ out){
  __shared__ float red[8][64][16];
  __shared__ float al[32], be[32];
  // XCD swizzle: XCDs 0-3 -> top tiles (read outT), XCDs 4-7 -> bottom (read out2T)
  const int bid = blockIdx.x;
  const int xcd = bid & 7, slot = bid >> 3;
  const int lb = (xcd < 4) ? (xcd * 32 + slot) : (128 + (xcd - 4) * 32 + slot);
  const int i0 = lb * 32;
  const bool top = lb < 128;
  const u16* BT   = top ? outT : out2T;
  const u16* denp = top ? pones : pbf;
  const int lane = threadIdx.x & 63, wv = threadIdx.x >> 6;
  const int r = lane & 31, h = lane >> 5;
  const int kw = wv * 1024;                       // wave's K-range: [kw, kw+1024)
  const int* ap = adj + (size_t)(i0 + r) * 8192 + kw + h * 8;
  const u16* bp = BT + (size_t)r * 8192 + kw + h * 8;
  const u16* dp = denp + h * 8;
  f32x16 acc[8] = {};
  f32x16 accD = {};
  i32x4 A0 = __builtin_nontemporal_load((const i32x4*)ap);
  i32x4 A1 = __builtin_nontemporal_load((const i32x4*)ap + 1);
  #pragma unroll 2
  for (int s = 0; s < 64; ++s){
    const i32x4* pf = (const i32x4*)(ap + (s < 63 ? 16 : 0));
    i32x4 N0 = __builtin_nontemporal_load(pf);
    i32x4 N1 = __builtin_nontemporal_load(pf + 1);
    // adj{0,1} -> packed bf16 pair: lo = a*0x3F80, hi = (a*0x3F8)<<20
    i32x4 pk = {
      (int)((u32)(A0[0] * 0x3F80) | ((u32)(A0[1] * 0x3F8) << 20)),
      (int)((u32)(A0[2] * 0x3F80) | ((u32)(A0[3] * 0x3F8) << 20)),
      (int)((u32)(A1[0] * 0x3F80) | ((u32)(A1[1] * 0x3F8) << 20)),
      (int)((u32)(A1[2] * 0x3F80) | ((u32)(A1[3] * 0x3F8) << 20)) };
    bf16x8 af = __builtin_bit_cast(bf16x8, pk);
    bf16x8 bd = {};
    if (r == 0) bd = *(const bf16x8*)(dp + ((kw + s * 16) & 4095));
    accD = __builtin_amdgcn_mfma_f32_32x32x16_bf16(af, bd, accD, 0, 0, 0);
    #pragma unroll
    for (int t = 0; t < 8; ++t){
      bf16x8 bf = *(const bf16x8*)(bp + (size_t)t * 32 * 8192 + s * 16);
      acc[t] = __builtin_amdgcn_mfma_f32_32x32x16_bf16(af, bf, acc[t], 0, 0, 0);
    }
    A0 = N0; A1 = N1; ap += 16;
  }
  // ---- epilogue: cross-wave reduce (waves 0-3 = K<4096, 4-7 = K>=4096) ----
  *(f32x16*)(&red[wv][lane][0]) = accD;
  __syncthreads();
  const int tid = threadIdx.x;
  if (tid < 32){
    const int le = 32 * ((tid >> 2) & 1);
    const int re = (tid & 3) | ((tid >> 3) << 2);
    float d0 = red[0][le][re] + red[1][le][re] + red[2][le][re] + red[3][le][re];
    float d1 = red[4][le][re] + red[5][le][re] + red[6][le][re] + red[7][le][re];
    float A, B;
    if (top){
      float va = v0[i0 + tid], vb = v1[i0 + tid];
      float m = fmaxf(va, vb);
      float e0 = __expf(va - m), e1 = __expf(vb - m);
      float D = e0 * d0 + e1 * d1;
      A = e0 / D; B = e1 / D;
    } else {
      float inv = 1.0f / (d0 + d1);
      A = inv; B = inv;
    }
    al[tid] = A; be[tid] = B;
  }
  __syncthreads();
  #pragma unroll
  for (int t = 0; t < 8; ++t){
    *(f32x16*)(&red[wv][lane][0]) = acc[t];
    __syncthreads();
    #pragma unroll
    for (int e2 = 0; e2 < 2; ++e2){
      int e = tid + e2 * 512;
      int le = e & 63, re = e >> 6;
      float S0 = red[0][le][re] + red[1][le][re] + red[2][le][re] + red[3][le][re];
      float S1 = red[4][le][re] + red[5][le][re] + red[6][le][re] + red[7][le][re];
      int rr = (re & 3) + 8 * (re >> 2) + 4 * (le >> 5);
      int nn = t * 32 + (le & 31);
      float xv = al[rr] * S0 + be[rr] * S1;
      float sg = 1.0f / (1.0f + __expf(-xv));
      __builtin_nontemporal_store(sg, out + (size_t)(i0 + rr) * 256 + nn);
    }
    __syncthreads();
  }
}

extern "C" void kernel_launch(void* const* d_in, const int* in_sizes, int n_in,
                              void* d_out, int out_size, void* d_ws, size_t ws_size,
                              hipStream_t stream)
{
  const float* x      = (const float*)d_in[0];
  const float* weight = (const float*)d_in[1];
  const float* av     = (const float*)d_in[2];
  const int*   adj    = (const int*)d_in[3];
  float* out = (float*)d_out;
  char* ws = (char*)d_ws;
  u16*   wT    = (u16*)(ws + 0);            // 262144 B
  u16*   outT  = (u16*)(ws + 262144);       // 4194304 B
  u16*   out2T = (u16*)(ws + 4456448);      // 4194304 B
  u16*   pbf   = (u16*)(ws + 8650752);      // 8192 B
  u16*   pones = (u16*)(ws + 8658944);      // 8192 B
  float* s1    = (float*)(ws + 8667136);    // 32768 B
  float* s2    = (float*)(ws + 8699904);    // 32768 B
  float* v0    = (float*)(ws + 8732672);    // 16384 B
  float* v1    = (float*)(ws + 8749056);    // 16384 B

  k0_wt    <<<512, 256, 0, stream>>>(weight, wT);
  k1_gemm  <<<256, 512, 0, stream>>>(x, wT, outT);
  k2a_s    <<<128, 64, 0, stream>>>(outT, av, s1, s2);
  k2b_p    <<<1, 1024, 0, stream>>>(s1, s2, v0, v1, pbf, pones);
  k2c_scale<<<1024, 256, 0, stream>>>(outT, pbf, out2T);
  k3_main  <<<256, 512, 0, stream>>>(adj, outT, out2T, pbf, pones, v0, v1, out);
}

// Round 2
// 162.513 us; speedup vs baseline: 2.1318x; 2.1318x over previous
//
#include <hip/hip_runtime.h>

using u32 = unsigned int;
using u16 = unsigned short;

typedef __attribute__((ext_vector_type(8)))  __bf16 bf16x8;
typedef __attribute__((ext_vector_type(16))) float  f32x16;
typedef __attribute__((ext_vector_type(4)))  float  f32x4;
typedef __attribute__((ext_vector_type(4)))  int    i32x4;

__device__ __forceinline__ u32 f2bf(float f){
  u32 u = __float_as_uint(f);
  return (u + 0x7FFFu + ((u >> 16) & 1u)) >> 16;
}
__device__ __forceinline__ u32 pack2bf(float lo, float hi){
  return f2bf(lo) | (f2bf(hi) << 16);
}
__device__ __forceinline__ float bfu2f(u32 us){ return __uint_as_float(us << 16); }
__device__ __forceinline__ float lrelu(float x){ return x > 0.f ? x : 0.01f * x; }

// ---------- K0: weight [512][256] f32 -> wT [256][512] bf16 (+ init M) ----------
__global__ void k0_wt(const float* __restrict__ w, u16* __restrict__ wT, float* __restrict__ M){
  if (blockIdx.x == 0 && threadIdx.x == 0) M[0] = 0.f;
  int u = blockIdx.x * 256 + threadIdx.x;
  int k = u >> 8, n = u & 255;
  wT[(size_t)n * 512 + k] = (u16)f2bf(w[(size_t)k * 256 + n]);
}

// ---------- K1: out = x@W -> outT [256][8192] bf16, plus s1/s2/v0/v1/max-w ----------
__global__ __launch_bounds__(512, 2) void k1_gemm(const float* __restrict__ x,
    const u16* __restrict__ wT, const float* __restrict__ av, u16* __restrict__ outT,
    float* __restrict__ s1, float* __restrict__ s2,
    float* __restrict__ v0, float* __restrict__ v1, float* __restrict__ M){
  __shared__ float tb[8][32][36];
  __shared__ float afl[512];
  __shared__ float sred[2][32][17];
  __shared__ float srw[2][32];
  const int i0 = blockIdx.x * 32;
  const int tid = threadIdx.x;
  const int lane = tid & 63, wv = tid >> 6;
  const int r = lane & 31, h = lane >> 5;
  const float* xp = x + (size_t)(i0 + r) * 512 + h * 8;
  const u16*   bp = wT + (size_t)(wv * 32 + r) * 512 + h * 8;
  f32x16 acc = {};
  for (int s = 0; s < 32; ++s){
    f32x4 a0 = *(const f32x4*)xp;
    f32x4 a1 = *(const f32x4*)(xp + 4);
    i32x4 pk = { (int)pack2bf(a0[0], a0[1]), (int)pack2bf(a0[2], a0[3]),
                 (int)pack2bf(a1[0], a1[1]), (int)pack2bf(a1[2], a1[3]) };
    bf16x8 af = __builtin_bit_cast(bf16x8, pk);
    bf16x8 bf = *(const bf16x8*)bp;
    acc = __builtin_amdgcn_mfma_f32_32x32x16_bf16(af, bf, acc, 0, 0, 0);
    xp += 16; bp += 16;
  }
  #pragma unroll
  for (int re = 0; re < 16; ++re){
    int rr = (re & 3) + 8 * (re >> 2) + 4 * h;
    tb[wv][r][rr] = acc[re];
  }
  afl[tid] = av[tid];
  __syncthreads();
  // outT write
  {
    const int n2 = lane >> 1, ic = (lane & 1) * 16;
    const float* tp = &tb[wv][n2][ic];
    i32x4 w0 = { (int)pack2bf(tp[0],tp[1]),   (int)pack2bf(tp[2],tp[3]),
                 (int)pack2bf(tp[4],tp[5]),   (int)pack2bf(tp[6],tp[7]) };
    i32x4 w1 = { (int)pack2bf(tp[8],tp[9]),   (int)pack2bf(tp[10],tp[11]),
                 (int)pack2bf(tp[12],tp[13]), (int)pack2bf(tp[14],tp[15]) };
    u16* op = outT + (size_t)(wv * 32 + n2) * 8192 + i0 + ic;
    *(i32x4*)op = w0;
    *((i32x4*)op + 1) = w1;
  }
  // s-dot: s1[row] = sum_f out[row][f]*a1[f], s2 likewise (f32-accurate from acc)
  const int row = tid & 31, g = tid >> 5;
  const int w8 = g >> 1, fh = (g & 1) * 16;
  float a1c = 0.f, a2c = 0.f;
  #pragma unroll
  for (int f = 0; f < 16; ++f){
    float tv = tb[w8][fh + f][row];
    a1c = fmaf(tv, afl[w8 * 32 + fh + f], a1c);
    a2c = fmaf(tv, afl[256 + w8 * 32 + fh + f], a2c);
  }
  sred[0][row][g] = a1c; sred[1][row][g] = a2c;
  __syncthreads();
  if (tid < 64){
    int which = tid >> 5, r2 = tid & 31;
    float s = 0.f;
    #pragma unroll
    for (int g2 = 0; g2 < 16; ++g2) s += sred[which][r2][g2];
    (which ? s2 : s1)[i0 + r2] = s;
    srw[which][r2] = s;
  }
  __syncthreads();
  if (tid < 16){
    int k = (i0 >> 1) + tid;
    float sa = srw[0][2*tid], sb = srw[1][2*tid];
    float sa1 = srw[0][2*tid+1], sb1 = srw[1][2*tid+1];
    v0[k] = lrelu(sa + sb);
    v1[k] = lrelu(sa1 + sb1);
    float wv_ = fmaxf(lrelu(sa + sb1), 0.f);
    #pragma unroll
    for (int off = 8; off; off >>= 1) wv_ = fmaxf(wv_, __shfl_down(wv_, off, 16));
    if (tid == 0) atomicMax((int*)M, __float_as_int(wv_));
  }
}

// ---------- K2b2: p = exp(w - M) -> pbf (bf16), pfbot (f32 of bf16), pftop = 1 ----------
__global__ void k2b2(const float* __restrict__ s1, const float* __restrict__ s2,
    const float* __restrict__ M, u16* __restrict__ pbf,
    float* __restrict__ pftop, float* __restrict__ pfbot){
  int k = blockIdx.x * 512 + threadIdx.x;
  float m = M[0];
  float w = lrelu(s1[2*k] + s2[2*k+1]);
  float p = __expf(w - m);
  u32 pb16 = f2bf(p);
  pbf[k] = (u16)pb16;
  pfbot[k] = bfu2f(pb16);
  pftop[k] = 1.0f;
}

// ---------- K2c: out2T[n][j] = p[j&4095] * outT[n][j] ----------
__global__ void k2c_scale(const u16* __restrict__ outT, const u16* __restrict__ pbf,
                          u16* __restrict__ out2T){
  const int u = blockIdx.x * 256 + threadIdx.x;
  const int n = u >> 10;
  const int j8 = (u & 1023) * 8;
  i32x4 ov = *(const i32x4*)(outT + (size_t)n * 8192 + j8);
  i32x4 pv = *(const i32x4*)(pbf + (j8 & 4095));
  i32x4 rv;
  #pragma unroll
  for (int q = 0; q < 4; ++q){
    u32 o = (u32)ov[q], p = (u32)pv[q];
    rv[q] = (int)pack2bf(bfu2f(o & 0xFFFFu) * bfu2f(p & 0xFFFFu),
                         bfu2f(o >> 16)     * bfu2f(p >> 16));
  }
  *(i32x4*)(out2T + (size_t)n * 8192 + j8) = rv;
}

// ---------- K3: LDS-staged binary GEMM, K-split partials ----------
// grid 512: xcd=bid&7 -> (half = xcd>>2, chunk c = xcd&3), slot = bid>>3
// block: 64 rows x 256 feats, K-chunk 2048, 8 waves x 32 feats, K_step 128
__global__ __launch_bounds__(512, 4) void k3_main(const int* __restrict__ adj,
    const u16* __restrict__ outT, const u16* __restrict__ out2T,
    const float* __restrict__ pftop, const float* __restrict__ pfbot,
    float* __restrict__ P, float* __restrict__ pd){
  __shared__ u16 Ab[2][64 * 136];    // 136 u16/row = 272 B: 17 x 16B slots -> bank spread
  __shared__ float dred[64][9];
  const int bid = blockIdx.x;
  const int xcd = bid & 7, slot = bid >> 3;
  const int c = xcd & 3, half = xcd >> 2;
  const int tile = half * 64 + slot;
  const int i0 = tile * 64, kbase = c * 2048;
  const int pb = (tile << 2) | c;
  const u16* BT = half ? out2T : outT;
  const float* pf = half ? pfbot : pftop;
  const int tid = threadIdx.x;
  const int lane = tid & 63, wv = tid >> 6;
  const int r = lane & 31, h = lane >> 5;
  const int fb = wv * 32;
  const int srow = tid >> 3, sseg = tid & 7;
  const int* aptr = adj + (size_t)(i0 + srow) * 8192 + kbase + sseg * 4;
  f32x16 acc0 = {}, acc1 = {};
  float d = 0.f;
  i32x4 ar[4]; f32x4 pr[4];

#define LOADT(t_) { const int kk = (t_) * 128; \
  _Pragma("unroll") for (int q = 0; q < 4; ++q){ \
    ar[q] = __builtin_nontemporal_load((const i32x4*)(aptr + kk + q * 32)); \
    pr[q] = *(const f32x4*)(pf + ((kbase + kk + q * 32 + sseg * 4) & 4095)); } }

#define STORET(t_) { u16* wb = &Ab[(t_) & 1][srow * 136 + sseg * 4]; \
  _Pragma("unroll") for (int q = 0; q < 4; ++q){ \
    i32x4 a = ar[q]; f32x4 p = pr[q]; \
    d = fmaf((float)a[0], p[0], d); d = fmaf((float)a[1], p[1], d); \
    d = fmaf((float)a[2], p[2], d); d = fmaf((float)a[3], p[3], d); \
    uint2 v; \
    v.x = (u32)(a[0] * 0x3F80) | ((u32)(a[1] * 0x3F8) << 20); \
    v.y = (u32)(a[2] * 0x3F80) | ((u32)(a[3] * 0x3F8) << 20); \
    *(uint2*)(wb + q * 32) = v; } }

  LOADT(0); STORET(0);
  __syncthreads();
  for (int t = 0; t < 16; ++t){
    if (t < 15) LOADT(t + 1);
    {
      const u16* ab = Ab[t & 1];
      const u16* bbase = BT + (size_t)(fb + r) * 8192 + kbase + t * 128 + h * 8;
      const u16* a0p = ab + r * 136 + h * 8;
      #pragma unroll
      for (int ks = 0; ks < 8; ++ks){
        bf16x8 bfv = *(const bf16x8*)(bbase + ks * 16);
        bf16x8 av0 = *(const bf16x8*)(a0p + ks * 16);
        bf16x8 av1 = *(const bf16x8*)(a0p + 32 * 136 + ks * 16);
        acc0 = __builtin_amdgcn_mfma_f32_32x32x16_bf16(av0, bfv, acc0, 0, 0, 0);
        acc1 = __builtin_amdgcn_mfma_f32_32x32x16_bf16(av1, bfv, acc1, 0, 0, 0);
      }
    }
    if (t < 15) STORET(t + 1);
    __syncthreads();
  }
#undef LOADT
#undef STORET
  dred[srow][sseg] = d;
  __syncthreads();
  if (tid < 64){
    float s = 0.f;
    #pragma unroll
    for (int q = 0; q < 8; ++q) s += dred[tid][q];
    pd[(size_t)pb * 64 + tid] = s;
  }
  float* Pb = P + (size_t)pb * 64 * 256 + fb + r;
  #pragma unroll
  for (int e = 0; e < 16; ++e){
    int rr0 = (e & 3) + 8 * (e >> 2) + 4 * h;
    __builtin_nontemporal_store(acc0[e], Pb + (size_t)rr0 * 256);
    __builtin_nontemporal_store(acc1[e], Pb + (size_t)(rr0 + 32) * 256);
  }
}

// ---------- K4: combine K-split partials + softmax coeffs + sigmoid ----------
__global__ void k4_final(const float* __restrict__ P, const float* __restrict__ pd,
    const float* __restrict__ v0, const float* __restrict__ v1, float* __restrict__ out){
  const int i = blockIdx.x, n = threadIdx.x;
  const int tile = i >> 6, rloc = i & 63;
  const size_t pb0 = (size_t)tile * 4;
  const size_t base = (pb0 * 64 + rloc) * 256 + n;
  float P0 = __builtin_nontemporal_load(P + base);
  float P1 = __builtin_nontemporal_load(P + base + 16384);
  float P2 = __builtin_nontemporal_load(P + base + 32768);
  float P3 = __builtin_nontemporal_load(P + base + 49152);
  const float* pdp = pd + pb0 * 64 + rloc;
  float d0 = pdp[0] + pdp[64], d1 = pdp[128] + pdp[192];
  float val;
  if (i < 4096){
    float va = v0[i], vb = v1[i];
    float m = fmaxf(va, vb);
    float e0 = __expf(va - m), e1 = __expf(vb - m);
    val = (e0 * (P0 + P1) + e1 * (P2 + P3)) / (e0 * d0 + e1 * d1);
  } else {
    val = (P0 + P1 + P2 + P3) / (d0 + d1);
  }
  out[(size_t)i * 256 + n] = 1.0f / (1.0f + __expf(-val));
}

extern "C" void kernel_launch(void* const* d_in, const int* in_sizes, int n_in,
                              void* d_out, int out_size, void* d_ws, size_t ws_size,
                              hipStream_t stream)
{
  const float* x      = (const float*)d_in[0];
  const float* weight = (const float*)d_in[1];
  const float* av     = (const float*)d_in[2];
  const int*   adj    = (const int*)d_in[3];
  float* out = (float*)d_out;
  char* ws = (char*)d_ws;
  float* P     = (float*)(ws + 0);             // 33,554,432 B
  float* pd    = (float*)(ws + 33554432);      //    131,072 B
  u16*   outT  = (u16*)  (ws + 33685504);      //  4,194,304 B
  u16*   out2T = (u16*)  (ws + 37879808);      //  4,194,304 B
  u16*   wT    = (u16*)  (ws + 42074112);      //    262,144 B
  u16*   pbf   = (u16*)  (ws + 42336256);      //      8,192 B
  float* pftop = (float*)(ws + 42344448);      //     16,384 B
  float* pfbot = (float*)(ws + 42360832);      //     16,384 B
  float* s1    = (float*)(ws + 42377216);      //     32,768 B
  float* s2    = (float*)(ws + 42409984);      //     32,768 B
  float* v0    = (float*)(ws + 42442752);      //     16,384 B
  float* v1    = (float*)(ws + 42459136);      //     16,384 B
  float* M     = (float*)(ws + 42475520);      //          4 B

  k0_wt    <<<512, 256, 0, stream>>>(weight, wT, M);
  k1_gemm  <<<256, 512, 0, stream>>>(x, wT, av, outT, s1, s2, v0, v1, M);
  k2b2     <<<8, 512, 0, stream>>>(s1, s2, M, pbf, pftop, pfbot);
  k2c_scale<<<1024, 256, 0, stream>>>(outT, pbf, out2T);
  k3_main  <<<512, 512, 0, stream>>>(adj, outT, out2T, pftop, pfbot, P, pd);
  k4_final <<<8192, 256, 0, stream>>>(P, pd, v0, v1, out);
}